// Round 10
// baseline (1359.288 us; speedup 1.0000x reference)
//
#include <hip/hip_runtime.h>

#define TSTEPS 2048
#define NBATCH 512
#define H1 64
#define H2 16

typedef _Float16 h2v __attribute__((ext_vector_type(2)));

__device__ __forceinline__ float fsig(float x) {
    return __builtin_amdgcn_rcpf(1.0f + __builtin_amdgcn_exp2f(-1.4426950408889634f * x));
}
__device__ __forceinline__ float ftanh(float x) {
    // tanh(x) = 1 - 2/(exp2(2x*log2e)+1); saturates correctly at +-inf
    return 1.0f - 2.0f * __builtin_amdgcn_rcpf(1.0f + __builtin_amdgcn_exp2f(2.8853900817779268f * x));
}
// branchless: k2==1 -> sigmoid(x); k2==2 -> tanh(x) = 2*sig(2x)-1
__device__ __forceinline__ float act(float x, float k2) {
    return k2 * fsig(k2 * x) - (k2 - 1.0f);
}

#if __has_builtin(__builtin_amdgcn_fdot2)
__device__ __forceinline__ float dot2(int wp, int hp, float acc) {
    return __builtin_amdgcn_fdot2(__builtin_bit_cast(h2v, wp),
                                  __builtin_bit_cast(h2v, hp), acc, false);
}
#else
__device__ __forceinline__ float dot2(int wp, int hp, float acc) {
    h2v a = __builtin_bit_cast(h2v, wp), b = __builtin_bit_cast(h2v, hp);
    return acc + (float)a.x * (float)b.x + (float)a.y * (float)b.y;
}
#endif

__device__ __forceinline__ int packh2(float a, float b) {
    h2v v; v.x = (_Float16)a; v.y = (_Float16)b;
    return __builtin_bit_cast(int, v);
}
template<int CTRL>
__device__ __forceinline__ float dpp_bcast(float v) {   // quad broadcast
    int r = __builtin_amdgcn_mov_dpp(__float_as_int(v), CTRL, 0xF, 0xF, true);
    return __int_as_float(r);
}

// ONE WAVE PER BATCH, ZERO BARRIERS (r9 structure, 1234 us) with the register
// fit actually achieved this time:
//  - amdgpu_num_vgpr(256): request the full arch-VGPR file (r9: allocator
//    silently targeted 4 waves/EU -> 128 regs -> ~130 dword/lane/step scratch
//    round-trips = the 3x gap between 1450 cyc/step measured and ~450 issue).
//  - w2/wh2 (40 regs) pinned to AGPRs ("+a"): off the v-budget entirely.
//  - h1 fragment reads 2-chunk pipelined: hp liveness 32 -> 16 regs.
__global__ void __launch_bounds__(64, 1)
__attribute__((amdgpu_num_vgpr(256)))
lstm2_fused(const float* __restrict__ x,      // [512, 2048, 1]
            const float* __restrict__ w_ih1,  // [256, 1]
            const float* __restrict__ w_hh1,  // [256, 64]
            const float* __restrict__ b_ih1,  // [256]
            const float* __restrict__ b_hh1,  // [256]
            const float* __restrict__ w_ih2,  // [64, 64]
            const float* __restrict__ w_hh2,  // [64, 16]
            const float* __restrict__ b_ih2,  // [64]
            const float* __restrict__ b_hh2,  // [64]
            float* __restrict__ out)          // [512, 2048, 16]
{
    const int lane = threadIdx.x;     // 64 threads = 1 wave
    const int b    = blockIdx.x;      // 1 batch per block

    __shared__ float    x_lds[TSTEPS];     // 8 KB
    __shared__ _Float16 h1_lds[H1];        // 128 B
    __shared__ _Float16 h2_lds[H2];        // 32 B
    __shared__ float    ring[32][H2];      // 2 KB output ring

    // ---- stage x[b,:] ----
    {
        const float4* xs = (const float4*)(x + (size_t)b * TSTEPS);
        float4* xd = (float4*)x_lds;
        #pragma unroll
        for (int i = 0; i < 8; ++i) xd[lane + 64 * i] = xs[lane + 64 * i];
    }
    if (lane < 32) ((int*)h1_lds)[lane] = 0;
    if (lane < 8)  ((int*)h2_lds)[lane] = 0;

    // ---- L1 weights: lane j; gate rows {j, 64+j, 128+j, 192+j}, k=0..63 ----
    int   w1[4][32];                   // packed f16 pairs (128 VGPRs)
    float wx1[4], bs1[4];
    #pragma unroll
    for (int g = 0; g < 4; ++g) {
        const int r = g * H1 + lane;
        const float* wr = w_hh1 + (size_t)r * H1;
        #pragma unroll
        for (int k = 0; k < 32; ++k) w1[g][k] = packh2(wr[2 * k], wr[2 * k + 1]);
        wx1[g] = w_ih1[r];
        bs1[g] = b_ih1[r] + b_hh1[r];
    }
    // ---- L2 weights: lane -> channel m = lane>>2, gate g2 = lane&3 ----
    const int m  = lane >> 2;
    const int g2 = lane & 3;
    const int r2 = g2 * H2 + m;
    int w2[32], wh2[8];                // pinned to AGPRs in-loop
    #pragma unroll
    for (int k = 0; k < 32; ++k)
        w2[k] = packh2(w_ih2[(size_t)r2 * H1 + 2 * k], w_ih2[(size_t)r2 * H1 + 2 * k + 1]);
    #pragma unroll
    for (int k = 0; k < 8; ++k)
        wh2[k] = packh2(w_hh2[(size_t)r2 * H2 + 2 * k], w_hh2[(size_t)r2 * H2 + 2 * k + 1]);
    const float bs2 = b_ih2[r2] + b_hh2[r2];
    const float k22 = (g2 == 2) ? 2.0f : 1.0f;

    float c1 = 0.0f;                  // cell of L1 channel j (lane-private)
    float c2 = 0.0f;                  // cell of L2 channel m (replicated per quad)
    float* outb = out + (size_t)b * TSTEPS * H2;

    for (int p = 0; p <= TSTEPS; ++p) {
        // in-loop opaque pins: w1 stays in VGPRs, w2/wh2 stay in AGPRs
        #pragma unroll
        for (int g = 0; g < 4; ++g)
            #pragma unroll
            for (int k = 0; k < 32; ++k) asm volatile("" : "+v"(w1[g][k]));
        #pragma unroll
        for (int k = 0; k < 32; ++k) asm volatile("" : "+a"(w2[k]));
        #pragma unroll
        for (int k = 0; k < 8; ++k)  asm volatile("" : "+a"(wh2[k]));

        // ---- output flush: every 16 steps, slots written 16-31 steps ago ----
        const int tau_f = p - 1;
        if (tau_f >= 31 && (tau_f & 15) == 15) {
            const int tau0 = (tau_f & ~15) - 16;
            const int tt = tau0 + (lane >> 2), ch0 = (lane & 3) * 4;
            float4 v = *(const float4*)&ring[tt & 31][ch0];
            *(float4*)(outb + (size_t)tt * H2 + ch0) = v;      // 1 KB coalesced
        }

        // ---- gate accumulators ----
        const float xv = x_lds[p & (TSTEPS - 1)];      // masked: p==TSTEPS unused
        float ai = bs1[0] + wx1[0] * xv;
        float af = bs1[1] + wx1[1] * xv;
        float ag = bs1[2] + wx1[2] * xv;
        float ao = bs1[3] + wx1[3] * xv;
        float a0 = bs2, a1 = 0.f, a2a = 0.f, a3 = 0.f;

        // ---- h1(p-1) in 2-chunk pipeline: liveness 16 regs, latency hidden ----
        {
            const int4* hs4 = (const int4*)h1_lds;
            int4 hA = hs4[0], hB = hs4[1];
            #pragma unroll
            for (int c = 0; c < 4; ++c) {
                int4 nA, nB;
                if (c < 3) { nA = hs4[2 * c + 2]; nB = hs4[2 * c + 3]; }
                const int h0 = hA.x, h1p = hA.y, h2p = hA.z, h3p = hA.w;
                const int h4p = hB.x, h5p = hB.y, h6p = hB.z, h7p = hB.w;
                // L1: 4 gate chains x 8 pairs
                ai = dot2(w1[0][8*c+0], h0, ai);  af = dot2(w1[1][8*c+0], h0, af);
                ag = dot2(w1[2][8*c+0], h0, ag);  ao = dot2(w1[3][8*c+0], h0, ao);
                ai = dot2(w1[0][8*c+1], h1p, ai); af = dot2(w1[1][8*c+1], h1p, af);
                ag = dot2(w1[2][8*c+1], h1p, ag); ao = dot2(w1[3][8*c+1], h1p, ao);
                ai = dot2(w1[0][8*c+2], h2p, ai); af = dot2(w1[1][8*c+2], h2p, af);
                ag = dot2(w1[2][8*c+2], h2p, ag); ao = dot2(w1[3][8*c+2], h2p, ao);
                ai = dot2(w1[0][8*c+3], h3p, ai); af = dot2(w1[1][8*c+3], h3p, af);
                ag = dot2(w1[2][8*c+3], h3p, ag); ao = dot2(w1[3][8*c+3], h3p, ao);
                ai = dot2(w1[0][8*c+4], h4p, ai); af = dot2(w1[1][8*c+4], h4p, af);
                ag = dot2(w1[2][8*c+4], h4p, ag); ao = dot2(w1[3][8*c+4], h4p, ao);
                ai = dot2(w1[0][8*c+5], h5p, ai); af = dot2(w1[1][8*c+5], h5p, af);
                ag = dot2(w1[2][8*c+5], h5p, ag); ao = dot2(w1[3][8*c+5], h5p, ao);
                ai = dot2(w1[0][8*c+6], h6p, ai); af = dot2(w1[1][8*c+6], h6p, af);
                ag = dot2(w1[2][8*c+6], h6p, ag); ao = dot2(w1[3][8*c+6], h6p, ao);
                ai = dot2(w1[0][8*c+7], h7p, ai); af = dot2(w1[1][8*c+7], h7p, af);
                ag = dot2(w1[2][8*c+7], h7p, ag); ao = dot2(w1[3][8*c+7], h7p, ao);
                // L2 ih-chains: 2 pairs per chain per chunk
                a0  = dot2(w2[8*c+0], h0,  a0);   a0  = dot2(w2[8*c+4], h4p, a0);
                a1  = dot2(w2[8*c+1], h1p, a1);   a1  = dot2(w2[8*c+5], h5p, a1);
                a2a = dot2(w2[8*c+2], h2p, a2a);  a2a = dot2(w2[8*c+6], h6p, a2a);
                a3  = dot2(w2[8*c+3], h3p, a3);   a3  = dot2(w2[8*c+7], h7p, a3);
                if (c < 3) { hA = nA; hB = nB; }
            }
        }

        // ===== Layer 1 finish, timestep p =====
        if (p < TSTEPS) {
            float gi = fsig(ai), gf = fsig(af), gg = ftanh(ag), go = fsig(ao);
            c1 = gf * c1 + gi * gg;
            float h1n = go * ftanh(c1);
            h1_lds[lane] = (_Float16)h1n;       // ds_write_b16; same-wave FIFO
        }

        // ===== Layer 2 finish, timestep p-1 (same wave, no sync) =====
        if (p >= 1) {
            int hq[8];
            {
                const int4* hs = (const int4*)h2_lds;   // h2(p-2)
                int4 u0 = hs[0], u1 = hs[1];
                hq[0]=u0.x; hq[1]=u0.y; hq[2]=u0.z; hq[3]=u0.w;
                hq[4]=u1.x; hq[5]=u1.y; hq[6]=u1.z; hq[7]=u1.w;
            }
            #pragma unroll
            for (int k = 0; k < 2; ++k) {       // w_hh2 (16 k)
                a0  = dot2(wh2[4*k+0], hq[4*k+0], a0);
                a1  = dot2(wh2[4*k+1], hq[4*k+1], a1);
                a2a = dot2(wh2[4*k+2], hq[4*k+2], a2a);
                a3  = dot2(wh2[4*k+3], hq[4*k+3], a3);
            }
            float av = act((a0 + a1) + (a2a + a3), k22);
            // gather the quad's 4 gates (i,f,g,o) via DPP broadcast
            float gi = dpp_bcast<0x00>(av);
            float gf = dpp_bcast<0x55>(av);
            float gg = dpp_bcast<0xAA>(av);
            float go = dpp_bcast<0xFF>(av);
            c2 = gf * c2 + gi * gg;
            float h2n = go * ftanh(c2);
            if (g2 == 0) {
                h2_lds[m] = (_Float16)h2n;
                ring[(p - 1) & 31][m] = h2n;
            }
        }
    }

    // ---- tail flush: timesteps 2032..2047 ----
    {
        const int tt = 2032 + (lane >> 2), ch0 = (lane & 3) * 4;
        float4 v = *(const float4*)&ring[tt & 31][ch0];
        *(float4*)(outb + (size_t)tt * H2 + ch0) = v;
    }
}

extern "C" void kernel_launch(void* const* d_in, const int* in_sizes, int n_in,
                              void* d_out, int out_size, void* d_ws, size_t ws_size,
                              hipStream_t stream) {
    const float* x     = (const float*)d_in[0];
    const float* w_ih1 = (const float*)d_in[1];
    const float* w_hh1 = (const float*)d_in[2];
    const float* b_ih1 = (const float*)d_in[3];
    const float* b_hh1 = (const float*)d_in[4];
    const float* w_ih2 = (const float*)d_in[5];
    const float* w_hh2 = (const float*)d_in[6];
    const float* b_ih2 = (const float*)d_in[7];
    const float* b_hh2 = (const float*)d_in[8];
    float* out = (float*)d_out;

    lstm2_fused<<<NBATCH, 64, 0, stream>>>(x, w_ih1, w_hh1, b_ih1, b_hh1,
                                           w_ih2, w_hh2, b_ih2, b_hh2, out);
}